// Round 2
// baseline (785.749 us; speedup 1.0000x reference)
//
#include <hip/hip_runtime.h>
#include <hip/hip_bf16.h>

#define VOCAB  32000
#define EMBED  32
#define HIDDEN 16
#define SEQ    128
#define BATCH  32

typedef __attribute__((ext_vector_type(8))) short short8;
typedef __attribute__((ext_vector_type(4))) float float4v;

#define LOG2E 1.4426950408889634f
#define LN2   0.6931471805599453f

__device__ __forceinline__ float fexp2(float x) { return __builtin_amdgcn_exp2f(x); }
__device__ __forceinline__ float frcp(float x)  { return __builtin_amdgcn_rcpf(x); }
__device__ __forceinline__ float flog2(float x) { return __builtin_amdgcn_logf(x); }

// RTNE float -> bf16 bits (finite inputs only)
__device__ __forceinline__ unsigned short f2bf(float x) {
    unsigned u = __float_as_uint(x);
    unsigned r = u + 0x7fffu + ((u >> 16) & 1u);
    return (unsigned short)(r >> 16);
}

// ---------------------------------------------------------------------------
// Kernel 0: convert W_out [32000][16] and b_out [32000] fp32 -> bf16 in ws.
// ---------------------------------------------------------------------------
__global__ __launch_bounds__(256) void k_convert(
    const float* __restrict__ W_out, const float* __restrict__ b_out,
    unsigned short* __restrict__ Wo16, unsigned short* __restrict__ bo16)
{
    int t4 = (blockIdx.x * 256 + threadIdx.x) * 4;
    const int NW = VOCAB * HIDDEN;                 // 512000
    if (t4 < NW) {
        float4 v = *(const float4*)(W_out + t4);
        Wo16[t4 + 0] = f2bf(v.x); Wo16[t4 + 1] = f2bf(v.y);
        Wo16[t4 + 2] = f2bf(v.z); Wo16[t4 + 3] = f2bf(v.w);
    } else if (t4 < NW + VOCAB) {
        int j = t4 - NW;
        float4 v = *(const float4*)(b_out + j);
        bo16[j + 0] = f2bf(v.x); bo16[j + 1] = f2bf(v.y);
        bo16[j + 2] = f2bf(v.z); bo16[j + 3] = f2bf(v.w);
    }
}

// ---------------------------------------------------------------------------
// Kernel 1: proj[v][j] = sum_e emb[v][e] * W_ih[j][e] + b_ih[j] + b_hh[j]
// fp32 throughout. grid 1000 x 256: j = tid&63, 4 row-groups of 8 rows.
// ---------------------------------------------------------------------------
__global__ __launch_bounds__(256) void k_proj(
    const float* __restrict__ emb,
    const float* __restrict__ W_ih,
    const float* __restrict__ b_ih,
    const float* __restrict__ b_hh,
    float* __restrict__ proj)
{
    int j  = threadIdx.x & 63;
    int vl = threadIdx.x >> 6;          // 0..3
    int vbase = blockIdx.x * 32 + vl * 8;

    float w[32];
    {
        const float4* wp = (const float4*)(W_ih + j * 32);
#pragma unroll
        for (int i = 0; i < 8; ++i) *((float4*)w + i) = wp[i];
    }
    float bias = b_ih[j] + b_hh[j];

#pragma unroll
    for (int r = 0; r < 8; ++r) {
        int v = vbase + r;
        float x[32];
        const float4* xp = (const float4*)(emb + v * 32);
#pragma unroll
        for (int i = 0; i < 8; ++i) *((float4*)x + i) = xp[i];
        float a0 = bias, a1 = 0.f;
#pragma unroll
        for (int i = 0; i < 16; ++i) {
            a0 += x[2*i]   * w[2*i];
            a1 += x[2*i+1] * w[2*i+1];
        }
        proj[(size_t)v * 64 + j] = a0 + a1;
    }
}

// ---------------------------------------------------------------------------
// Kernel 2: LSTM recurrence. 32 blocks (one per batch) x 1 wave.
// Lane j owns gate j (i:0-15, f:16-31, g:32-47, o:48-63). Wave-synchronous.
// ---------------------------------------------------------------------------
__global__ __launch_bounds__(64) void k_lstm(
    const int* __restrict__ idx,
    const float* __restrict__ proj,
    const float* __restrict__ W_hh,
    const float* __restrict__ h0,
    const float* __restrict__ c0,
    unsigned short* __restrict__ h_ws)
{
    int b = blockIdx.x;
    int j = threadIdx.x;

    float w[16];
    {
        const float4* wp = (const float4*)(W_hh + j * 16);
#pragma unroll
        for (int i = 0; i < 4; ++i) *((float4*)w + i) = wp[i];
    }

    int l15 = j & 15;
    float h = h0[b * HIDDEN + l15];
    float c = c0[b * HIDDEN + l15];

    // all 128 step-indices for this batch, 2 per lane
    int i0 = idx[j * BATCH + b];
    int i1 = idx[(j + 64) * BATCH + b];

    // prefetch projected inputs for s=0,1
    float xg0 = proj[(size_t)__shfl(i0, 0) * 64 + j];
    float xg1 = proj[(size_t)__shfl(i0, 1) * 64 + j];

    for (int s = 0; s < SEQ; ++s) {
        float xg = xg0;
        xg0 = xg1;
        if (s + 2 < SEQ) {
            int sn = s + 2;
            int idn = __shfl((sn < 64) ? i0 : i1, sn & 63);
            xg1 = proj[(size_t)idn * 64 + j];
        }

        float a0 = xg, a1 = 0.f;
#pragma unroll
        for (int k = 0; k < 8; ++k) {
            a0 += w[2*k]   * __shfl(h, 2*k);
            a1 += w[2*k+1] * __shfl(h, 2*k+1);
        }
        float acc = a0 + a1;

        // sigmoid for i,f,o; tanh for g (lanes 32-47)
        float e1 = fexp2(-acc * LOG2E);
        float sg = frcp(1.f + e1);
        float e2 = fexp2(-2.f * acc * LOG2E);
        float th = 2.f * frcp(1.f + e2) - 1.f;
        float act = ((j >> 4) == 2) ? th : sg;

        float i_ = __shfl(act, l15);
        float f_ = __shfl(act, l15 + 16);
        float g_ = __shfl(act, l15 + 32);
        float o_ = __shfl(act, l15 + 48);

        c = f_ * c + i_ * g_;
        float e3 = fexp2(-2.f * c * LOG2E);
        float hc = 2.f * frcp(1.f + e3) - 1.f;   // tanh(c)
        h = o_ * hc;

        if (j < 16)
            h_ws[(size_t)(s * BATCH + b) * HIDDEN + j] = f2bf(h);
    }
}

// ---------------------------------------------------------------------------
// Kernel 3: logits + log-softmax. 256 blocks x 512 thr (8 waves).
// Block = 16 (s,b) rows x full vocab. MFMA 16x16x32 bf16:
//   A = W_out tile [16 vocab x K], B = h tile [K x 16 rows],
//   K: 0..15 = hidden, 16 = bias slot (A=b_out, B=1.0), 17..31 = zero.
// D: lane(n,q) holds D[vocab=v0+4q+r][row=r0+n] -> float4 store per lane.
// Logits bounded (|h|<1, |W|,|b|<=0.25): no max-subtraction needed.
// ---------------------------------------------------------------------------
__global__ __launch_bounds__(512) void k_logits(
    const unsigned short* __restrict__ Wo16,
    const unsigned short* __restrict__ bo16,
    const unsigned short* __restrict__ h_ws,
    float* __restrict__ out)
{
    __shared__ float sums[8][16];

    int r0   = blockIdx.x * 16;
    int tid  = threadIdx.x;
    int wave = tid >> 6;
    int lane = tid & 63;
    int n = lane & 15;        // B column (s,b row) / A row (vocab) local idx
    int q = lane >> 4;        // quad

    // B-frag: h rows (constant over vocab loop)
    short8 bfrag = {0, 0, 0, 0, 0, 0, 0, 0};
    if (q < 2)
        bfrag = *(const short8*)(h_ws + (size_t)(r0 + n) * 16 + 8 * q);
    else if (q == 2)
        bfrag[0] = (short)0x3F80;   // 1.0 bf16 in K-slot 16 (bias row)

    const int NT = VOCAB / (16 * 8);   // 250 tiles per wave

    // ---- pass 1: per-row sum of exp(y) ----
    float s0 = 0.f, s1 = 0.f, s2 = 0.f, s3 = 0.f;

    short8 a_cur = {0, 0, 0, 0, 0, 0, 0, 0};
    {
        int v0 = wave * 16;
        if (q < 2)       a_cur = *(const short8*)(Wo16 + (size_t)(v0 + n) * 16 + 8 * q);
        else if (q == 2) a_cur[0] = (short)bo16[v0 + n];
    }
    for (int t = 0; t < NT; ++t) {
        short8 a_nxt = {0, 0, 0, 0, 0, 0, 0, 0};
        if (t + 1 < NT) {
            int v0 = ((t + 1) * 8 + wave) * 16;
            if (q < 2)       a_nxt = *(const short8*)(Wo16 + (size_t)(v0 + n) * 16 + 8 * q);
            else if (q == 2) a_nxt[0] = (short)bo16[v0 + n];
        }
        float4v dz = {0.f, 0.f, 0.f, 0.f};
        float4v d = __builtin_amdgcn_mfma_f32_16x16x32_bf16(a_cur, bfrag, dz, 0, 0, 0);
        s0 += fexp2(d[0] * LOG2E);
        s1 += fexp2(d[1] * LOG2E);
        s2 += fexp2(d[2] * LOG2E);
        s3 += fexp2(d[3] * LOG2E);
        a_cur = a_nxt;
    }
    float ssum = (s0 + s1) + (s2 + s3);
    ssum += __shfl_xor(ssum, 16);
    ssum += __shfl_xor(ssum, 32);
    if (q == 0) sums[wave][n] = ssum;
    __syncthreads();

    float tot = 0.f;
#pragma unroll
    for (int wv = 0; wv < 8; ++wv) tot += sums[wv][n];
    float K = flog2(tot) * LN2;   // ln(sum exp(y)) for this lane's row

    // ---- pass 2: recompute logits, write y - K as fp32 ----
    {
        int v0 = wave * 16;
        short8 a0 = {0, 0, 0, 0, 0, 0, 0, 0};
        if (q < 2)       a0 = *(const short8*)(Wo16 + (size_t)(v0 + n) * 16 + 8 * q);
        else if (q == 2) a0[0] = (short)bo16[v0 + n];
        a_cur = a0;
    }
    size_t row_base = (size_t)(r0 + n) * VOCAB;
    for (int t = 0; t < NT; ++t) {
        short8 a_nxt = {0, 0, 0, 0, 0, 0, 0, 0};
        if (t + 1 < NT) {
            int v0 = ((t + 1) * 8 + wave) * 16;
            if (q < 2)       a_nxt = *(const short8*)(Wo16 + (size_t)(v0 + n) * 16 + 8 * q);
            else if (q == 2) a_nxt[0] = (short)bo16[v0 + n];
        }
        int v0 = (t * 8 + wave) * 16;
        float4v dz = {0.f, 0.f, 0.f, 0.f};
        float4v d = __builtin_amdgcn_mfma_f32_16x16x32_bf16(a_cur, bfrag, dz, 0, 0, 0);
        float4v ov;
        ov[0] = d[0] - K;
        ov[1] = d[1] - K;
        ov[2] = d[2] - K;
        ov[3] = d[3] - K;
        *(float4v*)(out + row_base + v0 + 4 * q) = ov;
        a_cur = a_nxt;
    }
}

// ---------------------------------------------------------------------------
extern "C" void kernel_launch(void* const* d_in, const int* in_sizes, int n_in,
                              void* d_out, int out_size, void* d_ws, size_t ws_size,
                              hipStream_t stream)
{
    const int*   idx   = (const int*)d_in[0];
    const float* emb   = (const float*)d_in[1];
    const float* W_ih  = (const float*)d_in[2];
    const float* W_hh  = (const float*)d_in[3];
    const float* b_ih  = (const float*)d_in[4];
    const float* b_hh  = (const float*)d_in[5];
    const float* W_out = (const float*)d_in[6];
    const float* b_out = (const float*)d_in[7];
    const float* h0    = (const float*)d_in[8];
    const float* c0    = (const float*)d_in[9];

    // workspace layout:
    //   proj  [32000][64] fp32 : 8.192 MB
    //   Wo16  [32000][16] bf16 : 1.024 MB
    //   bo16  [32000]     bf16 : 64 KB
    //   h_ws  [4096][16]  bf16 : 128 KB
    char* p = (char*)d_ws;
    float*          proj = (float*)p;                      p += (size_t)VOCAB * 64 * 4;
    unsigned short* Wo16 = (unsigned short*)p;             p += (size_t)VOCAB * 16 * 2;
    unsigned short* bo16 = (unsigned short*)p;             p += (size_t)VOCAB * 2;
    unsigned short* h_ws = (unsigned short*)p;

    const int NCVT = (VOCAB * HIDDEN + VOCAB) / 4;         // 136000 threads
    k_convert<<<(NCVT + 255) / 256, 256, 0, stream>>>(W_out, b_out, Wo16, bo16);
    k_proj<<<VOCAB / 32, 256, 0, stream>>>(emb, W_ih, b_ih, b_hh, proj);
    k_lstm<<<BATCH, 64, 0, stream>>>(idx, proj, W_hh, h0, c0, h_ws);
    k_logits<<<(SEQ * BATCH) / 16, 512, 0, stream>>>(Wo16, bo16, h_ws, (float*)d_out);
}